// Round 1
// baseline (245.172 us; speedup 1.0000x reference)
//
#include <hip/hip_runtime.h>
#include <cstdint>
#include <cstddef>

// ---- types ----
typedef __attribute__((ext_vector_type(8))) short short8;       // 8 bf16 (4 VGPR) MFMA frag
typedef __attribute__((ext_vector_type(4))) float floatx4;      // MFMA accumulator
typedef __attribute__((ext_vector_type(4))) unsigned short ushortx4; // 8B packed bf16 store
typedef __attribute__((ext_vector_type(4))) unsigned int uintx4;     // 16B vector ld/st

#define MFMA16(a, b, c) __builtin_amdgcn_mfma_f32_16x16x32_bf16((a), (b), (c), 0, 0, 0)

__device__ __forceinline__ unsigned short f2bf(float f) {
  unsigned int u = __builtin_bit_cast(unsigned int, f);
  u += 0x7fffu + ((u >> 16) & 1u);          // RNE
  return (unsigned short)(u >> 16);
}

typedef __attribute__((address_space(1))) void gvoid_t;
typedef __attribute__((address_space(3))) void svoid_t;
__device__ __forceinline__ void gload_lds16(const void* g, void* l) {
  // dest = wave-uniform LDS base + lane*16 (guide §5); casts via uintptr per CK convention
  __builtin_amdgcn_global_load_lds((gvoid_t*)(uintptr_t)g, (svoid_t*)(uintptr_t)l, 16, 0, 0);
}

// ---------------- convert x: fp32 -> bf16 ----------------
__global__ void convert_x(const float* __restrict__ x, unsigned short* __restrict__ xb) {
  int i = (blockIdx.x * 256 + threadIdx.x) * 4;
  floatx4 v = *(const floatx4*)(x + i);
  ushortx4 o;
  o[0] = f2bf(v[0]); o[1] = f2bf(v[1]); o[2] = f2bf(v[2]); o[3] = f2bf(v[3]);
  *(ushortx4*)(xb + i) = o;
}

// ---------------- transpose weights -> bf16 N x K ----------------
__global__ void transpose_w(const float* __restrict__ Wq, const float* __restrict__ Wk,
                            const float* __restrict__ Wv, const float* __restrict__ Wo,
                            unsigned short* __restrict__ Wqkvt, unsigned short* __restrict__ Wot) {
  __shared__ float tile[32][33];
  int z = blockIdx.z;
  const float* W = (z == 0) ? Wq : (z == 1) ? Wk : (z == 2) ? Wv : Wo;
  unsigned short* out = (z == 3) ? Wot : (Wqkvt + (size_t)z * 1024 * 1024);
  int n0 = blockIdx.x * 32, k0 = blockIdx.y * 32;
  int tx = threadIdx.x, ty = threadIdx.y;            // block (32,8)
#pragma unroll
  for (int j = 0; j < 4; ++j)
    tile[ty + j * 8][tx] = W[(size_t)(k0 + ty + j * 8) * 1024 + n0 + tx];
  __syncthreads();
#pragma unroll
  for (int j = 0; j < 4; ++j)
    out[(size_t)(n0 + ty + j * 8) * 1024 + k0 + tx] = f2bf(tile[tx][ty + j * 8]);
}

// ---------------- GEMM core (m97-style): C[m][n] = sum_k A[m][k]*Bt[n][k] ----------------
// 128x128 tile, BK=32, 256 thr = 4 waves (2x2), each wave 64x64 = 4x4 MFMA tiles.
#define GEMM_PROLOGUE()                                                        \
  __shared__ __align__(16) unsigned short As[128 * 32];                        \
  __shared__ __align__(16) unsigned short Bs[128 * 32];                        \
  const int tid = threadIdx.x;                                                 \
  const int lane = tid & 63;                                                   \
  const int wid = tid >> 6;                                                    \
  const int col = lane & 15;                                                   \
  const int quad = lane >> 4;                                                  \
  const int m0 = blockIdx.x * 128;                                             \
  const int n0 = blockIdx.y * 128;                                             \
  const int wm = wid >> 1;                                                     \
  const int wn = wid & 1;                                                      \
  floatx4 acc[4][4];                                                           \
  _Pragma("unroll") for (int i = 0; i < 4; ++i)                                \
      _Pragma("unroll") for (int j = 0; j < 4; ++j)                            \
          acc[i][j] = (floatx4){0.f, 0.f, 0.f, 0.f};                           \
  _Pragma("unroll 1") for (int kt = 0; kt < 32; ++kt) {                        \
    __syncthreads();                                                           \
    _Pragma("unroll") for (int call = 0; call < 2; ++call) {                   \
      int c = call * 256 + tid;                                                \
      int r = c >> 2, kc = c & 3;                                              \
      unsigned short* lb = As + (size_t)(call * 256 + wid * 64) * 8;           \
      gload_lds16(A + (size_t)(m0 + r) * 1024 + kt * 32 + kc * 8, lb);         \
      unsigned short* lb2 = Bs + (size_t)(call * 256 + wid * 64) * 8;          \
      gload_lds16(Bt + (size_t)(n0 + r) * 1024 + kt * 32 + kc * 8, lb2);       \
    }                                                                          \
    __syncthreads();                                                           \
    short8 af[4], bf[4];                                                       \
    _Pragma("unroll") for (int rt = 0; rt < 4; ++rt)                           \
        af[rt] = *(const short8*)&As[(wm * 64 + rt * 16 + col) * 32 + quad * 8];\
    _Pragma("unroll") for (int ct = 0; ct < 4; ++ct)                           \
        bf[ct] = *(const short8*)&Bs[(wn * 64 + ct * 16 + col) * 32 + quad * 8];\
    _Pragma("unroll") for (int rt = 0; rt < 4; ++rt)                           \
        _Pragma("unroll") for (int ct = 0; ct < 4; ++ct)                       \
            acc[rt][ct] = MFMA16(af[rt], bf[ct], acc[rt][ct]);                 \
  }

__global__ __launch_bounds__(256)
void gemm_qkv(const unsigned short* __restrict__ A, const unsigned short* __restrict__ Bt,
              const float* __restrict__ bq, const float* __restrict__ bk,
              const float* __restrict__ bv,
              unsigned short* __restrict__ Qo, unsigned short* __restrict__ Ko,
              unsigned short* __restrict__ Vo) {
  GEMM_PROLOGUE()
  // epilogue: n in [n0, n0+128) lies in one 1024-segment (q/k/v)
  const int nseg = n0 >> 10;
  const float* bias = (nseg == 0) ? bq : ((nseg == 1) ? bk : bv);
#pragma unroll
  for (int rt = 0; rt < 4; ++rt) {
#pragma unroll
    for (int ct = 0; ct < 4; ++ct) {
      int mg = m0 + wm * 64 + rt * 16 + quad * 4;   // +i, all 4 within same b
      int ng = n0 + wn * 64 + ct * 16 + col;
      int c = ng & 1023;
      int hh = c >> 6, hd = c & 63;
      int b_ = mg >> 11, s = mg & 2047;
      float bb = bias[c];
      if (nseg == 2) {
        // V stored transposed: Vo[bh][hd][s]; 4 consecutive s -> 8B packed store
        ushortx4 pk;
#pragma unroll
        for (int i = 0; i < 4; ++i) pk[i] = f2bf(acc[rt][ct][i] + bb);
        *(ushortx4*)&Vo[(size_t)(b_ * 16 + hh) * 131072 + (size_t)hd * 2048 + s] = pk;
      } else {
        unsigned short* dst =
            ((nseg == 0) ? Qo : Ko) + ((size_t)(b_ * 16 + hh) * 2048 + s) * 64 + hd;
        float scl = (nseg == 0) ? 0.125f : 1.0f;    // fold 1/sqrt(64) into Q (exact pow2)
#pragma unroll
        for (int i = 0; i < 4; ++i) dst[(size_t)i * 64] = f2bf((acc[rt][ct][i] + bb) * scl);
      }
    }
  }
}

__global__ __launch_bounds__(256)
void gemm_out(const unsigned short* __restrict__ A, const unsigned short* __restrict__ Bt,
              const float* __restrict__ bo, float* __restrict__ Out) {
  GEMM_PROLOGUE()
#pragma unroll
  for (int rt = 0; rt < 4; ++rt) {
#pragma unroll
    for (int ct = 0; ct < 4; ++ct) {
      int mg = m0 + wm * 64 + rt * 16 + quad * 4;
      int ng = n0 + wn * 64 + ct * 16 + col;
      float bb = bo[ng];
#pragma unroll
      for (int i = 0; i < 4; ++i)
        Out[(size_t)(mg + i) * 1024 + ng] = acc[rt][ct][i] + bb;
    }
  }
}

// ---------------- flash attention ----------------
// Per block: one (b,h), 128 q rows. S^T = K*Q^T so softmax stats are per-lane (q = lane&15),
// P exits with 4 consecutive kv per lane (8B packed LDS writes), PV computed as O^T = V^T*P^T.
__global__ __launch_bounds__(256, 2)
void flash_attn(const unsigned short* __restrict__ Q, const unsigned short* __restrict__ K,
                const unsigned short* __restrict__ Vt, const float* __restrict__ mask,
                unsigned short* __restrict__ O) {
  __shared__ __align__(16) unsigned short KP[128][136]; // K tile (cols 0..63) / P tile (0..127)
  __shared__ __align__(16) unsigned short Vs[64][136];  // V^T tile [hd][kv]
  __shared__ __align__(16) float mb[128];               // padding-mask additive bias

  const int tid = threadIdx.x;
  const int lane = tid & 63;
  const int wid = tid >> 6;
  const int col = lane & 15;
  const int quad = lane >> 4;
  const int qb = blockIdx.x;
  const int bh = blockIdx.y;
  const int b = bh >> 4;
  const int h = bh & 15;
  const int q0 = qb * 128;

  const unsigned short* Qp = Q + (size_t)bh * 2048 * 64;
  const unsigned short* Kp = K + (size_t)bh * 2048 * 64;
  const unsigned short* Vp = Vt + (size_t)bh * 64 * 2048;
  const float* mp = mask + b * 2048;

  // stage Q tile into KP region, read Q fragments (B-operand layout) once
#pragma unroll
  for (int i = 0; i < 4; ++i) {
    int c = tid + i * 256;
    int r = c >> 3, ch = c & 7;
    *(uintx4*)&KP[r][ch * 8] = *(const uintx4*)(Qp + (size_t)(q0 + r) * 64 + ch * 8);
  }
  __syncthreads();
  short8 qf[2][2];
#pragma unroll
  for (int qt = 0; qt < 2; ++qt)
#pragma unroll
    for (int ks = 0; ks < 2; ++ks)
      qf[qt][ks] = *(const short8*)&KP[wid * 32 + qt * 16 + col][ks * 32 + quad * 8];

  floatx4 o[4][2];
#pragma unroll
  for (int dt = 0; dt < 4; ++dt)
#pragma unroll
    for (int qt = 0; qt < 2; ++qt) o[dt][qt] = (floatx4){0.f, 0.f, 0.f, 0.f};
  float mrow[2] = {-1e30f, -1e30f};
  float lrow[2] = {0.f, 0.f};

#pragma unroll 1
  for (int t = 0; t <= qb; ++t) {
    __syncthreads();  // (1) prior-iter KP/Vs reads complete
#pragma unroll
    for (int i = 0; i < 4; ++i) {
      int c = tid + i * 256;
      int r = c >> 3, ch = c & 7;
      *(uintx4*)&KP[r][ch * 8] = *(const uintx4*)(Kp + (size_t)(t * 128 + r) * 64 + ch * 8);
    }
#pragma unroll
    for (int i = 0; i < 4; ++i) {
      int c = tid + i * 256;
      int r = c >> 4, ch = c & 15;
      *(uintx4*)&Vs[r][ch * 8] = *(const uintx4*)(Vp + (size_t)r * 2048 + t * 128 + ch * 8);
    }
    if (tid < 128) mb[tid] = (1.0f - mp[t * 128 + tid]) * -1.0e9f;
    __syncthreads();  // (2) staging visible

    // S^T tile: [kv=128][q=32 per wave]
    floatx4 sc[8][2];
#pragma unroll
    for (int rt = 0; rt < 8; ++rt) {
      sc[rt][0] = (floatx4){0.f, 0.f, 0.f, 0.f};
      sc[rt][1] = (floatx4){0.f, 0.f, 0.f, 0.f};
      short8 kf0 = *(const short8*)&KP[rt * 16 + col][quad * 8];
      short8 kf1 = *(const short8*)&KP[rt * 16 + col][32 + quad * 8];
      sc[rt][0] = MFMA16(kf0, qf[0][0], sc[rt][0]);
      sc[rt][0] = MFMA16(kf1, qf[0][1], sc[rt][0]);
      sc[rt][1] = MFMA16(kf0, qf[1][0], sc[rt][1]);
      sc[rt][1] = MFMA16(kf1, qf[1][1], sc[rt][1]);
    }
    // padding-mask bias (kv = rt*16 + quad*4 + i)
#pragma unroll
    for (int rt = 0; rt < 8; ++rt) {
      floatx4 bias = *(const floatx4*)&mb[rt * 16 + quad * 4];
      sc[rt][0] += bias;
      sc[rt][1] += bias;
    }
    if (t == qb) {  // diagonal tile: causal mask, exactly -1e9 like the reference
#pragma unroll
      for (int rt = 0; rt < 8; ++rt)
#pragma unroll
        for (int qt = 0; qt < 2; ++qt) {
          int qloc = wid * 32 + qt * 16 + col;
#pragma unroll
          for (int i = 0; i < 4; ++i)
            if (rt * 16 + quad * 4 + i > qloc) sc[rt][qt][i] = -1.0e9f;
        }
    }
    __syncthreads();  // (3) all waves done reading KP as K

#pragma unroll
    for (int qt = 0; qt < 2; ++qt) {
      float mt = -1e30f;
#pragma unroll
      for (int rt = 0; rt < 8; ++rt)
        mt = fmaxf(mt, fmaxf(fmaxf(sc[rt][qt][0], sc[rt][qt][1]),
                             fmaxf(sc[rt][qt][2], sc[rt][qt][3])));
      mt = fmaxf(mt, __shfl_xor(mt, 16));
      mt = fmaxf(mt, __shfl_xor(mt, 32));
      float mn = fmaxf(mrow[qt], mt);
      float alpha = __expf(mrow[qt] - mn);
      mrow[qt] = mn;
      float sum = 0.f;
#pragma unroll
      for (int rt = 0; rt < 8; ++rt)
#pragma unroll
        for (int i = 0; i < 4; ++i) {
          float p = __expf(sc[rt][qt][i] - mn);
          sc[rt][qt][i] = p;
          sum += p;
        }
      sum += __shfl_xor(sum, 16);
      sum += __shfl_xor(sum, 32);
      lrow[qt] = lrow[qt] * alpha + sum;
#pragma unroll
      for (int dt = 0; dt < 4; ++dt) o[dt][qt] *= alpha;
      // write P (own wave's q rows) as [q][kv]: 4 consecutive kv -> 8B packed
      int qloc = wid * 32 + qt * 16 + col;
#pragma unroll
      for (int rt = 0; rt < 8; ++rt) {
        ushortx4 pk;
#pragma unroll
        for (int i = 0; i < 4; ++i) pk[i] = f2bf(sc[rt][qt][i]);
        *(ushortx4*)&KP[qloc][rt * 16 + quad * 4] = pk;
      }
    }
    // PV: O^T[d][q] += V^T * P^T (own-wave P rows -> no barrier; DS ops in-order per wave)
#pragma unroll
    for (int ks = 0; ks < 4; ++ks) {
      short8 pf0 = *(const short8*)&KP[wid * 32 + col][ks * 32 + quad * 8];
      short8 pf1 = *(const short8*)&KP[wid * 32 + 16 + col][ks * 32 + quad * 8];
#pragma unroll
      for (int dt = 0; dt < 4; ++dt) {
        short8 vf = *(const short8*)&Vs[dt * 16 + col][ks * 32 + quad * 8];
        o[dt][0] = MFMA16(vf, pf0, o[dt][0]);
        o[dt][1] = MFMA16(vf, pf1, o[dt][1]);
      }
    }
  }

  // epilogue: O^T regs: d = dt*16 + quad*4 + i (consecutive i), q = l&15 + qt*16
#pragma unroll
  for (int qt = 0; qt < 2; ++qt) {
    float inv = 1.0f / lrow[qt];
    int qg = q0 + wid * 32 + qt * 16 + col;
    unsigned short* dst = O + ((size_t)(b * 2048 + qg)) * 1024 + h * 64;
#pragma unroll
    for (int dt = 0; dt < 4; ++dt) {
      ushortx4 pk;
#pragma unroll
      for (int i = 0; i < 4; ++i) pk[i] = f2bf(o[dt][qt][i] * inv);
      *(ushortx4*)&dst[dt * 16 + quad * 4] = pk;
    }
  }
}

// ---------------- launch ----------------
extern "C" void kernel_launch(void* const* d_in, const int* in_sizes, int n_in,
                              void* d_out, int out_size, void* d_ws, size_t ws_size,
                              hipStream_t stream) {
  (void)in_sizes; (void)n_in; (void)out_size; (void)ws_size;
  const float* x  = (const float*)d_in[0];
  const float* mask = (const float*)d_in[1];
  const float* Wq = (const float*)d_in[2];
  const float* bq = (const float*)d_in[3];
  const float* Wk = (const float*)d_in[4];
  const float* bk = (const float*)d_in[5];
  const float* Wv = (const float*)d_in[6];
  const float* bv = (const float*)d_in[7];
  const float* Wo = (const float*)d_in[8];
  const float* bo = (const float*)d_in[9];
  float* out = (float*)d_out;

  char* ws = (char*)d_ws;
  unsigned short* xb    = (unsigned short*)(ws);                    // 8 MB
  unsigned short* Wqkvt = (unsigned short*)(ws + (8u << 20));       // 6 MB
  unsigned short* Wot   = (unsigned short*)(ws + (14u << 20));      // 2 MB
  unsigned short* Qb    = (unsigned short*)(ws + (16u << 20));      // 8 MB
  unsigned short* Kb    = (unsigned short*)(ws + (24u << 20));      // 8 MB
  unsigned short* Vtb   = (unsigned short*)(ws + (32u << 20));      // 8 MB
  unsigned short* Ao    = (unsigned short*)(ws + (40u << 20));      // 8 MB (48 MB total)

  convert_x<<<4096, 256, 0, stream>>>(x, xb);
  transpose_w<<<dim3(32, 32, 4), dim3(32, 8), 0, stream>>>(Wq, Wk, Wv, Wo, Wqkvt, Wot);
  gemm_qkv<<<dim3(32, 24), 256, 0, stream>>>(xb, Wqkvt, bq, bk, bv, Qb, Kb, Vtb);
  flash_attn<<<dim3(16, 32), 256, 0, stream>>>(Qb, Kb, Vtb, mask, Ao);
  gemm_out<<<dim3(32, 8), 256, 0, stream>>>(Ao, Wot, bo, out);
}

// Round 3
// 238.940 us; speedup vs baseline: 1.0261x; 1.0261x over previous
//
#include <hip/hip_runtime.h>
#include <cstdint>
#include <cstddef>

// ---- types ----
typedef __attribute__((ext_vector_type(8))) short short8;       // 8 bf16 (4 VGPR) MFMA frag
typedef __attribute__((ext_vector_type(4))) float floatx4;      // MFMA accumulator
typedef __attribute__((ext_vector_type(4))) unsigned short ushortx4; // 8B packed bf16 store
typedef __attribute__((ext_vector_type(4))) unsigned int uintx4;     // 16B vector ld/st

#define MFMA16(a, b, c) __builtin_amdgcn_mfma_f32_16x16x32_bf16((a), (b), (c), 0, 0, 0)

__device__ __forceinline__ unsigned short f2bf(float f) {
  unsigned int u = __builtin_bit_cast(unsigned int, f);
  u += 0x7fffu + ((u >> 16) & 1u);          // RNE
  return (unsigned short)(u >> 16);
}

typedef __attribute__((address_space(1))) void gvoid_t;
typedef __attribute__((address_space(3))) void svoid_t;
__device__ __forceinline__ void gload_lds16(const void* g, void* l) {
  // LDS dest = wave-uniform base + lane*16; global side is per-lane addresses.
  __builtin_amdgcn_global_load_lds((gvoid_t*)(uintptr_t)g, (svoid_t*)(uintptr_t)l, 16, 0, 0);
}

// ---------------- convert x: fp32 -> bf16 ----------------
__global__ void convert_x(const float* __restrict__ x, unsigned short* __restrict__ xb) {
  int i = (blockIdx.x * 256 + threadIdx.x) * 4;
  floatx4 v = *(const floatx4*)(x + i);
  ushortx4 o;
  o[0] = f2bf(v[0]); o[1] = f2bf(v[1]); o[2] = f2bf(v[2]); o[3] = f2bf(v[3]);
  *(ushortx4*)(xb + i) = o;
}

// ---------------- transpose weights -> bf16 N x K ----------------
__global__ void transpose_w(const float* __restrict__ Wq, const float* __restrict__ Wk,
                            const float* __restrict__ Wv, const float* __restrict__ Wo,
                            unsigned short* __restrict__ Wqkvt, unsigned short* __restrict__ Wot) {
  __shared__ float tile[32][33];
  int z = blockIdx.z;
  const float* W = (z == 0) ? Wq : (z == 1) ? Wk : (z == 2) ? Wv : Wo;
  unsigned short* out = (z == 3) ? Wot : (Wqkvt + (size_t)z * 1024 * 1024);
  int n0 = blockIdx.x * 32, k0 = blockIdx.y * 32;
  int tx = threadIdx.x, ty = threadIdx.y;            // block (32,8)
#pragma unroll
  for (int j = 0; j < 4; ++j)
    tile[ty + j * 8][tx] = W[(size_t)(k0 + ty + j * 8) * 1024 + n0 + tx];
  __syncthreads();
#pragma unroll
  for (int j = 0; j < 4; ++j)
    out[(size_t)(n0 + ty + j * 8) * 1024 + k0 + tx] = f2bf(tile[tx][ty + j * 8]);
}

// ---------------- GEMM core (m97-style): C[m][n] = sum_k A[m][k]*Bt[n][k] ----------------
#define GEMM_PROLOGUE()                                                        \
  __shared__ __align__(16) unsigned short As[128 * 32];                        \
  __shared__ __align__(16) unsigned short Bs[128 * 32];                        \
  const int tid = threadIdx.x;                                                 \
  const int lane = tid & 63;                                                   \
  const int wid = tid >> 6;                                                    \
  const int col = lane & 15;                                                   \
  const int quad = lane >> 4;                                                  \
  const int m0 = blockIdx.x * 128;                                             \
  const int n0 = blockIdx.y * 128;                                             \
  const int wm = wid >> 1;                                                     \
  const int wn = wid & 1;                                                      \
  floatx4 acc[4][4];                                                           \
  _Pragma("unroll") for (int i = 0; i < 4; ++i)                                \
      _Pragma("unroll") for (int j = 0; j < 4; ++j)                            \
          acc[i][j] = (floatx4)(0.f);                                          \
  _Pragma("unroll 1") for (int kt = 0; kt < 32; ++kt) {                        \
    __syncthreads();                                                           \
    _Pragma("unroll") for (int call = 0; call < 2; ++call) {                   \
      int c = call * 256 + tid;                                                \
      int r = c >> 2, kc = c & 3;                                              \
      unsigned short* lb = As + (size_t)(call * 256 + wid * 64) * 8;           \
      gload_lds16(A + (size_t)(m0 + r) * 1024 + kt * 32 + kc * 8, lb);         \
      unsigned short* lb2 = Bs + (size_t)(call * 256 + wid * 64) * 8;          \
      gload_lds16(Bt + (size_t)(n0 + r) * 1024 + kt * 32 + kc * 8, lb2);       \
    }                                                                          \
    __syncthreads();                                                           \
    short8 af[4], bf[4];                                                       \
    _Pragma("unroll") for (int rt = 0; rt < 4; ++rt)                           \
        af[rt] = *(const short8*)&As[(wm * 64 + rt * 16 + col) * 32 + quad * 8];\
    _Pragma("unroll") for (int ct = 0; ct < 4; ++ct)                           \
        bf[ct] = *(const short8*)&Bs[(wn * 64 + ct * 16 + col) * 32 + quad * 8];\
    _Pragma("unroll") for (int rt = 0; rt < 4; ++rt)                           \
        _Pragma("unroll") for (int ct = 0; ct < 4; ++ct)                       \
            acc[rt][ct] = MFMA16(af[rt], bf[ct], acc[rt][ct]);                 \
  }

__global__ __launch_bounds__(256)
void gemm_qkv(const unsigned short* __restrict__ A, const unsigned short* __restrict__ Bt,
              const float* __restrict__ bq, const float* __restrict__ bk,
              const float* __restrict__ bv,
              unsigned short* __restrict__ Qo, unsigned short* __restrict__ Ko,
              unsigned short* __restrict__ Vo) {
  GEMM_PROLOGUE()
  const int nseg = n0 >> 10;
  const float* bias = (nseg == 0) ? bq : ((nseg == 1) ? bk : bv);
#pragma unroll
  for (int rt = 0; rt < 4; ++rt) {
#pragma unroll
    for (int ct = 0; ct < 4; ++ct) {
      int mg = m0 + wm * 64 + rt * 16 + quad * 4;
      int ng = n0 + wn * 64 + ct * 16 + col;
      int c = ng & 1023;
      int hh = c >> 6, hd = c & 63;
      int b_ = mg >> 11, s = mg & 2047;
      float bb = bias[c];
      if (nseg == 2) {
        ushortx4 pk;
#pragma unroll
        for (int i = 0; i < 4; ++i) pk[i] = f2bf(acc[rt][ct][i] + bb);
        *(ushortx4*)&Vo[(size_t)(b_ * 16 + hh) * 131072 + (size_t)hd * 2048 + s] = pk;
      } else {
        unsigned short* dst =
            ((nseg == 0) ? Qo : Ko) + ((size_t)(b_ * 16 + hh) * 2048 + s) * 64 + hd;
        float scl = (nseg == 0) ? 0.125f : 1.0f;
#pragma unroll
        for (int i = 0; i < 4; ++i) dst[(size_t)i * 64] = f2bf((acc[rt][ct][i] + bb) * scl);
      }
    }
  }
}

__global__ __launch_bounds__(256)
void gemm_out(const unsigned short* __restrict__ A, const unsigned short* __restrict__ Bt,
              const float* __restrict__ bo, float* __restrict__ Out) {
  GEMM_PROLOGUE()
#pragma unroll
  for (int rt = 0; rt < 4; ++rt) {
#pragma unroll
    for (int ct = 0; ct < 4; ++ct) {
      int mg = m0 + wm * 64 + rt * 16 + quad * 4;
      int ng = n0 + wn * 64 + ct * 16 + col;
      float bb = bo[ng];
#pragma unroll
      for (int i = 0; i < 4; ++i)
        Out[(size_t)(mg + i) * 1024 + ng] = acc[rt][ct][i] + bb;
    }
  }
}

// ---------------- flash attention v2 ----------------
// Block = (pair p, bh). Processes q-tiles j=p and j=15-p sequentially -> uniform 17 kv-iters.
// XOR-swizzled LDS (16B chunk ^ row), conflict-free; K/V/Q staged via global_load_lds
// (swizzle applied to the per-lane GLOBAL address, LDS side stays lane-linear).
// S^T = K*Q^T (softmax stats per-lane, q=lane&15); PV as O^T = V^T*P^T with per-wave-private P rows.
__global__ __launch_bounds__(256, 1)
void flash_attn(const unsigned short* __restrict__ Q, const unsigned short* __restrict__ K,
                const unsigned short* __restrict__ Vt, const float* __restrict__ mask,
                unsigned short* __restrict__ O) {
  __shared__ __align__(16) unsigned short Ks[128 * 64];   // [r][c8], chunk^(r&7)
  __shared__ __align__(16) unsigned short Vs[64 * 128];   // [r][c16], chunk^(r&15)
  __shared__ __align__(16) unsigned short Ps[128 * 128];  // [q][c16], chunk^q; Q stage = [128][64]

  const int tid = threadIdx.x;
  const int lane = tid & 63;
  const int wid = tid >> 6;
  const int col = lane & 15;
  const int quad = lane >> 4;
  const int pr = blockIdx.x;       // pair 0..7
  const int bh = blockIdx.y;
  const int b = bh >> 4, h = bh & 15;

  const unsigned short* Qp = Q + (size_t)bh * 2048 * 64;
  const unsigned short* Kp = K + (size_t)bh * 2048 * 64;
  const unsigned short* Vp = Vt + (size_t)bh * 64 * 2048;
  const float* mp = mask + b * 2048;

  const int lr8 = lane >> 3, lc8 = lane & 7;    // K/Q staging lane coords (8 rows x 8 chunks)
  const int lr16 = lane >> 4, lc16 = lane & 15; // V staging lane coords (4 rows x 16 chunks)
  const floatx4 fzero = (floatx4)(0.f);
  const floatx4 fone = (floatx4)(1.f);

#pragma unroll 1
  for (int phase = 0; phase < 2; ++phase) {
    const int j = phase ? (15 - pr) : pr;
    const int q0 = j * 128;

    __syncthreads();  // prior phase's Ks/Vs/Ps reads complete
    // stage Q tile [128][64] into Ps (swizzled): LDS[r][c] = Q[r][c ^ (r&7)]
#pragma unroll
    for (int i = 0; i < 4; ++i) {
      int seg = wid * 4 + i;
      int r = seg * 8 + lr8;
      gload_lds16(Qp + (size_t)(q0 + r) * 64 + ((lc8 ^ (r & 7)) * 8), Ps + seg * 512);
    }
    __syncthreads();
    short8 qf[2][2];
#pragma unroll
    for (int qt = 0; qt < 2; ++qt) {
      int q = wid * 32 + qt * 16 + col;
#pragma unroll
      for (int ks = 0; ks < 2; ++ks)
        qf[qt][ks] = *(const short8*)&Ps[q * 64 + (((ks * 4 + quad) ^ (q & 7)) * 8)];
    }
    // NOTE: first P write is ordered after all qf reads by the post-staging barrier of t=0.

    floatx4 o[4][2];
#pragma unroll
    for (int dt = 0; dt < 4; ++dt)
#pragma unroll
      for (int qt = 0; qt < 2; ++qt) o[dt][qt] = fzero;
    float mrow[2] = {-1e30f, -1e30f};
    float lrow[2] = {0.f, 0.f};

#pragma unroll 1
    for (int t = 0; t <= j; ++t) {
      if (t > 0) __syncthreads();  // prior iter's Ks/Vs frag reads done
#pragma unroll
      for (int i = 0; i < 4; ++i) {  // K tile [128][64]
        int seg = wid * 4 + i;
        int r = seg * 8 + lr8;
        gload_lds16(Kp + (size_t)(t * 128 + r) * 64 + ((lc8 ^ (r & 7)) * 8), Ks + seg * 512);
      }
#pragma unroll
      for (int i = 0; i < 4; ++i) {  // V^T tile [64][128]
        int seg = wid * 4 + i;
        int r = seg * 4 + lr16;
        gload_lds16(Vp + (size_t)r * 2048 + t * 128 + ((lc16 ^ (r & 15)) * 8), Vs + seg * 512);
      }
      __syncthreads();  // staging visible (vmcnt drained by barrier semantics)

      // padding-mask additive bias, per-lane from global (L1-resident; kv = rt*16+quad*4+i)
      floatx4 mbias[8];
#pragma unroll
      for (int rt = 0; rt < 8; ++rt) {
        floatx4 mm = *(const floatx4*)&mp[t * 128 + rt * 16 + quad * 4];
        mbias[rt] = (fone - mm) * -1.0e9f;
      }

      // S^T: [kv=128][q=32 per wave]
      floatx4 sc[8][2];
#pragma unroll
      for (int rt = 0; rt < 8; ++rt) {
        int kr = rt * 16 + col;
        short8 kf0 = *(const short8*)&Ks[kr * 64 + ((quad ^ (col & 7)) * 8)];
        short8 kf1 = *(const short8*)&Ks[kr * 64 + (((4 + quad) ^ (col & 7)) * 8)];
        floatx4 s0 = MFMA16(kf0, qf[0][0], fzero);
        s0 = MFMA16(kf1, qf[0][1], s0);
        floatx4 s1 = MFMA16(kf0, qf[1][0], fzero);
        s1 = MFMA16(kf1, qf[1][1], s1);
        sc[rt][0] = s0;
        sc[rt][1] = s1;
      }
#pragma unroll
      for (int rt = 0; rt < 8; ++rt) {
        sc[rt][0] += mbias[rt];
        sc[rt][1] += mbias[rt];
      }
      if (t == j) {  // diagonal tile: causal mask, exactly -1e9 like the reference
#pragma unroll
        for (int rt = 0; rt < 8; ++rt)
#pragma unroll
          for (int qt = 0; qt < 2; ++qt) {
            int qloc = wid * 32 + qt * 16 + col;
#pragma unroll
            for (int i = 0; i < 4; ++i)
              if (rt * 16 + quad * 4 + i > qloc) sc[rt][qt][i] = -1.0e9f;
          }
      }

#pragma unroll
      for (int qt = 0; qt < 2; ++qt) {
        float mt = -1e30f;
#pragma unroll
        for (int rt = 0; rt < 8; ++rt)
          mt = fmaxf(mt, fmaxf(fmaxf(sc[rt][qt][0], sc[rt][qt][1]),
                               fmaxf(sc[rt][qt][2], sc[rt][qt][3])));
        mt = fmaxf(mt, __shfl_xor(mt, 16));
        mt = fmaxf(mt, __shfl_xor(mt, 32));
        float mn = fmaxf(mrow[qt], mt);
        float alpha = __expf(mrow[qt] - mn);
        mrow[qt] = mn;
        float sum = 0.f;
#pragma unroll
        for (int rt = 0; rt < 8; ++rt)
#pragma unroll
          for (int i = 0; i < 4; ++i) {
            float p = __expf(sc[rt][qt][i] - mn);
            sc[rt][qt][i] = p;
            sum += p;
          }
        sum += __shfl_xor(sum, 16);
        sum += __shfl_xor(sum, 32);
        lrow[qt] = lrow[qt] * alpha + sum;
#pragma unroll
        for (int dt = 0; dt < 4; ++dt) o[dt][qt] *= alpha;
        // write P rows (own wave) swizzled: 8B at chunk (rt*2 + quad>>1) ^ col, half quad&1
        int qloc = wid * 32 + qt * 16 + col;
#pragma unroll
        for (int rt = 0; rt < 8; ++rt) {
          ushortx4 pk;
#pragma unroll
          for (int i = 0; i < 4; ++i) pk[i] = f2bf(sc[rt][qt][i]);
          int chunk = (rt * 2 + (quad >> 1)) ^ col;
          *(ushortx4*)&Ps[qloc * 128 + chunk * 8 + (quad & 1) * 4] = pk;
        }
      }
      // PV: O^T[d][q] += V^T * P^T (own-wave P rows; DS in-order per wave, no barrier)
#pragma unroll
      for (int ks = 0; ks < 4; ++ks) {
        int ch = ks * 4 + quad;
        short8 pf0 = *(const short8*)&Ps[(wid * 32 + col) * 128 + ((ch ^ col) * 8)];
        short8 pf1 = *(const short8*)&Ps[(wid * 32 + 16 + col) * 128 + ((ch ^ col) * 8)];
#pragma unroll
        for (int dt = 0; dt < 4; ++dt) {
          short8 vf = *(const short8*)&Vs[(dt * 16 + col) * 128 + ((ch ^ col) * 8)];
          o[dt][0] = MFMA16(vf, pf0, o[dt][0]);
          o[dt][1] = MFMA16(vf, pf1, o[dt][1]);
        }
      }
    }

    // epilogue: O^T regs: d = dt*16 + quad*4 + i, q = qt*16 + col (+wid*32)
#pragma unroll
    for (int qt = 0; qt < 2; ++qt) {
      float inv = 1.0f / lrow[qt];
      int qg = q0 + wid * 32 + qt * 16 + col;
      unsigned short* dst = O + ((size_t)(b * 2048 + qg)) * 1024 + h * 64;
#pragma unroll
      for (int dt = 0; dt < 4; ++dt) {
        ushortx4 pk;
#pragma unroll
        for (int i = 0; i < 4; ++i) pk[i] = f2bf(o[dt][qt][i] * inv);
        *(ushortx4*)&dst[dt * 16 + quad * 4] = pk;
      }
    }
  }
}

// ---------------- launch ----------------
extern "C" void kernel_launch(void* const* d_in, const int* in_sizes, int n_in,
                              void* d_out, int out_size, void* d_ws, size_t ws_size,
                              hipStream_t stream) {
  (void)in_sizes; (void)n_in; (void)out_size; (void)ws_size;
  const float* x  = (const float*)d_in[0];
  const float* mask = (const float*)d_in[1];
  const float* Wq = (const float*)d_in[2];
  const float* bq = (const float*)d_in[3];
  const float* Wk = (const float*)d_in[4];
  const float* bk = (const float*)d_in[5];
  const float* Wv = (const float*)d_in[6];
  const float* bv = (const float*)d_in[7];
  const float* Wo = (const float*)d_in[8];
  const float* bo = (const float*)d_in[9];
  float* out = (float*)d_out;

  char* ws = (char*)d_ws;
  unsigned short* xb    = (unsigned short*)(ws);                    // 8 MB
  unsigned short* Wqkvt = (unsigned short*)(ws + (8u << 20));       // 6 MB
  unsigned short* Wot   = (unsigned short*)(ws + (14u << 20));      // 2 MB
  unsigned short* Qb    = (unsigned short*)(ws + (16u << 20));      // 8 MB
  unsigned short* Kb    = (unsigned short*)(ws + (24u << 20));      // 8 MB
  unsigned short* Vtb   = (unsigned short*)(ws + (32u << 20));      // 8 MB
  unsigned short* Ao    = (unsigned short*)(ws + (40u << 20));      // 8 MB (48 MB total)

  convert_x<<<4096, 256, 0, stream>>>(x, xb);
  transpose_w<<<dim3(32, 32, 4), dim3(32, 8), 0, stream>>>(Wq, Wk, Wv, Wo, Wqkvt, Wot);
  gemm_qkv<<<dim3(32, 24), 256, 0, stream>>>(xb, Wqkvt, bq, bk, bv, Qb, Kb, Vtb);
  flash_attn<<<dim3(8, 32), 256, 0, stream>>>(Qb, Kb, Vtb, mask, Ao);
  gemm_out<<<dim3(32, 8), 256, 0, stream>>>(Ao, Wot, bo, out);
}

// Round 4
// 229.922 us; speedup vs baseline: 1.0663x; 1.0392x over previous
//
#include <hip/hip_runtime.h>
#include <cstdint>
#include <cstddef>

// ---- types ----
typedef __attribute__((ext_vector_type(8))) short short8;       // 8 bf16 (4 VGPR) MFMA frag
typedef __attribute__((ext_vector_type(4))) float floatx4;      // MFMA accumulator
typedef __attribute__((ext_vector_type(4))) unsigned short ushortx4; // 8B packed bf16 store
typedef __attribute__((ext_vector_type(4))) unsigned int uintx4;     // 16B vector ld/st

#define MFMA16(a, b, c) __builtin_amdgcn_mfma_f32_16x16x32_bf16((a), (b), (c), 0, 0, 0)

__device__ __forceinline__ unsigned short f2bf(float f) {
  unsigned int u = __builtin_bit_cast(unsigned int, f);
  u += 0x7fffu + ((u >> 16) & 1u);          // RNE
  return (unsigned short)(u >> 16);
}

typedef __attribute__((address_space(1))) void gvoid_t;
typedef __attribute__((address_space(3))) void svoid_t;
__device__ __forceinline__ void gload_lds16(const void* g, void* l) {
  // LDS dest = wave-uniform base + lane*16; global side is per-lane addresses.
  __builtin_amdgcn_global_load_lds((gvoid_t*)(uintptr_t)g, (svoid_t*)(uintptr_t)l, 16, 0, 0);
}

// ---------------- convert x: fp32 -> bf16 ----------------
__global__ void convert_x(const float* __restrict__ x, unsigned short* __restrict__ xb) {
  int i = (blockIdx.x * 256 + threadIdx.x) * 4;
  floatx4 v = *(const floatx4*)(x + i);
  ushortx4 o;
  o[0] = f2bf(v[0]); o[1] = f2bf(v[1]); o[2] = f2bf(v[2]); o[3] = f2bf(v[3]);
  *(ushortx4*)(xb + i) = o;
}

// ---------------- transpose weights -> bf16 N x K ----------------
__global__ void transpose_w(const float* __restrict__ Wq, const float* __restrict__ Wk,
                            const float* __restrict__ Wv, const float* __restrict__ Wo,
                            unsigned short* __restrict__ Wqkvt, unsigned short* __restrict__ Wot) {
  __shared__ float tile[32][33];
  int z = blockIdx.z;
  const float* W = (z == 0) ? Wq : (z == 1) ? Wk : (z == 2) ? Wv : Wo;
  unsigned short* out = (z == 3) ? Wot : (Wqkvt + (size_t)z * 1024 * 1024);
  int n0 = blockIdx.x * 32, k0 = blockIdx.y * 32;
  int tx = threadIdx.x, ty = threadIdx.y;            // block (32,8)
#pragma unroll
  for (int j = 0; j < 4; ++j)
    tile[ty + j * 8][tx] = W[(size_t)(k0 + ty + j * 8) * 1024 + n0 + tx];
  __syncthreads();
#pragma unroll
  for (int j = 0; j < 4; ++j)
    out[(size_t)(n0 + ty + j * 8) * 1024 + k0 + tx] = f2bf(tile[tx][ty + j * 8]);
}

// ---------------- GEMM core (m97-style): C[m][n] = sum_k A[m][k]*Bt[n][k] ----------------
#define GEMM_PROLOGUE()                                                        \
  __shared__ __align__(16) unsigned short As[128 * 32];                        \
  __shared__ __align__(16) unsigned short Bs[128 * 32];                        \
  const int tid = threadIdx.x;                                                 \
  const int lane = tid & 63;                                                   \
  const int wid = tid >> 6;                                                    \
  const int col = lane & 15;                                                   \
  const int quad = lane >> 4;                                                  \
  const int m0 = blockIdx.x * 128;                                             \
  const int n0 = blockIdx.y * 128;                                             \
  const int wm = wid >> 1;                                                     \
  const int wn = wid & 1;                                                      \
  floatx4 acc[4][4];                                                           \
  _Pragma("unroll") for (int i = 0; i < 4; ++i)                                \
      _Pragma("unroll") for (int j = 0; j < 4; ++j)                            \
          acc[i][j] = (floatx4)(0.f);                                          \
  _Pragma("unroll 1") for (int kt = 0; kt < 32; ++kt) {                        \
    __syncthreads();                                                           \
    _Pragma("unroll") for (int call = 0; call < 2; ++call) {                   \
      int c = call * 256 + tid;                                                \
      int r = c >> 2, kc = c & 3;                                              \
      unsigned short* lb = As + (size_t)(call * 256 + wid * 64) * 8;           \
      gload_lds16(A + (size_t)(m0 + r) * 1024 + kt * 32 + kc * 8, lb);         \
      unsigned short* lb2 = Bs + (size_t)(call * 256 + wid * 64) * 8;          \
      gload_lds16(Bt + (size_t)(n0 + r) * 1024 + kt * 32 + kc * 8, lb2);       \
    }                                                                          \
    __syncthreads();                                                           \
    short8 af[4], bf[4];                                                       \
    _Pragma("unroll") for (int rt = 0; rt < 4; ++rt)                           \
        af[rt] = *(const short8*)&As[(wm * 64 + rt * 16 + col) * 32 + quad * 8];\
    _Pragma("unroll") for (int ct = 0; ct < 4; ++ct)                           \
        bf[ct] = *(const short8*)&Bs[(wn * 64 + ct * 16 + col) * 32 + quad * 8];\
    _Pragma("unroll") for (int rt = 0; rt < 4; ++rt)                           \
        _Pragma("unroll") for (int ct = 0; ct < 4; ++ct)                       \
            acc[rt][ct] = MFMA16(af[rt], bf[ct], acc[rt][ct]);                 \
  }

__global__ __launch_bounds__(256)
void gemm_qkv(const unsigned short* __restrict__ A, const unsigned short* __restrict__ Bt,
              const float* __restrict__ bq, const float* __restrict__ bk,
              const float* __restrict__ bv,
              unsigned short* __restrict__ Qo, unsigned short* __restrict__ Ko,
              unsigned short* __restrict__ Vo) {
  GEMM_PROLOGUE()
  const int nseg = n0 >> 10;
  const float* bias = (nseg == 0) ? bq : ((nseg == 1) ? bk : bv);
#pragma unroll
  for (int rt = 0; rt < 4; ++rt) {
#pragma unroll
    for (int ct = 0; ct < 4; ++ct) {
      int mg = m0 + wm * 64 + rt * 16 + quad * 4;
      int ng = n0 + wn * 64 + ct * 16 + col;
      int c = ng & 1023;
      int hh = c >> 6, hd = c & 63;
      int b_ = mg >> 11, s = mg & 2047;
      float bb = bias[c];
      if (nseg == 2) {
        ushortx4 pk;
#pragma unroll
        for (int i = 0; i < 4; ++i) pk[i] = f2bf(acc[rt][ct][i] + bb);
        *(ushortx4*)&Vo[(size_t)(b_ * 16 + hh) * 131072 + (size_t)hd * 2048 + s] = pk;
      } else {
        unsigned short* dst =
            ((nseg == 0) ? Qo : Ko) + ((size_t)(b_ * 16 + hh) * 2048 + s) * 64 + hd;
        float scl = (nseg == 0) ? 0.125f : 1.0f;
#pragma unroll
        for (int i = 0; i < 4; ++i) dst[(size_t)i * 64] = f2bf((acc[rt][ct][i] + bb) * scl);
      }
    }
  }
}

__global__ __launch_bounds__(256)
void gemm_out(const unsigned short* __restrict__ A, const unsigned short* __restrict__ Bt,
              const float* __restrict__ bo, float* __restrict__ Out) {
  GEMM_PROLOGUE()
#pragma unroll
  for (int rt = 0; rt < 4; ++rt) {
#pragma unroll
    for (int ct = 0; ct < 4; ++ct) {
      int mg = m0 + wm * 64 + rt * 16 + quad * 4;
      int ng = n0 + wn * 64 + ct * 16 + col;
      float bb = bo[ng];
#pragma unroll
      for (int i = 0; i < 4; ++i)
        Out[(size_t)(mg + i) * 1024 + ng] = acc[rt][ct][i] + bb;
    }
  }
}

// ---------------- flash attention v3 ----------------
// Q-tile = 64 rows, kv-tile = 128. Block = (pair p, bh): q-tiles j=p and j=31-p
// sequentially -> uniform 17 kv-iters/block. Grid 512 -> 2-3 blocks/CU resident
// (LDS 48 KiB) so barrier stalls of one block overlap compute of others.
// XOR-swizzled LDS; each wave owns 16 q rows (stages its own Q, private P rows).
__global__ __launch_bounds__(256, 3)
void flash_attn(const unsigned short* __restrict__ Q, const unsigned short* __restrict__ K,
                const unsigned short* __restrict__ Vt, const float* __restrict__ mask,
                unsigned short* __restrict__ O) {
  __shared__ __align__(16) unsigned short Ks[128 * 64];   // [r][c8], chunk^(r&7)
  __shared__ __align__(16) unsigned short Vs[64 * 128];   // [r][c16], chunk^(r&15)
  __shared__ __align__(16) unsigned short Ps[64 * 128];   // P [q][c16] chunk^col; Q stage [64][64]

  const int tid = threadIdx.x;
  const int lane = tid & 63;
  const int wid = tid >> 6;
  const int col = lane & 15;
  const int quad = lane >> 4;
  const int pr = blockIdx.x;       // pair 0..15
  const int bh = blockIdx.y;
  const int b = bh >> 4, h = bh & 15;

  const unsigned short* Qp = Q + (size_t)bh * 2048 * 64;
  const unsigned short* Kp = K + (size_t)bh * 2048 * 64;
  const unsigned short* Vp = Vt + (size_t)bh * 64 * 2048;
  const float* mp = mask + b * 2048;

  const int lr8 = lane >> 3, lc8 = lane & 7;    // K/Q staging lane coords (8 rows x 8 chunks)
  const int lr16 = lane >> 4, lc16 = lane & 15; // V staging lane coords (4 rows x 16 chunks)
  const floatx4 fzero = (floatx4)(0.f);
  const floatx4 fone = (floatx4)(1.f);

#pragma unroll 1
  for (int phase = 0; phase < 2; ++phase) {
    const int j = phase ? (31 - pr) : pr;      // q-tile index (64 rows)
    const int q0 = j * 64;
    const int tdiag = j >> 1;                  // diagonal kv-tile (128 wide)

    __syncthreads();  // prior phase's Ks/Vs/Ps reads complete
    // stage own Q rows [64][64] into Ps (swizzled): LDS[r][c] = Q[r][c ^ (r&7)]
#pragma unroll
    for (int i = 0; i < 2; ++i) {
      int seg = wid * 2 + i;
      int r = seg * 8 + lr8;
      gload_lds16(Qp + (size_t)(q0 + r) * 64 + ((lc8 ^ (r & 7)) * 8), Ps + seg * 512);
    }
    __syncthreads();  // lgkm+vm drained: staged Q visible
    short8 qf[2];
    {
      int q = wid * 16 + col;
#pragma unroll
      for (int ks = 0; ks < 2; ++ks)
        qf[ks] = *(const short8*)&Ps[q * 64 + (((ks * 4 + quad) ^ (q & 7)) * 8)];
    }
    // First P write is ordered after all waves' qf reads by the t=0 post-staging barrier.

    floatx4 o[4];
#pragma unroll
    for (int dt = 0; dt < 4; ++dt) o[dt] = fzero;
    float mrow = -1e30f;
    float lrow = 0.f;

#pragma unroll 1
    for (int t = 0; t <= tdiag; ++t) {
      if (t > 0) __syncthreads();  // prior iter's Ks/Vs frag reads done
#pragma unroll
      for (int i = 0; i < 4; ++i) {  // K tile [128][64]
        int seg = wid * 4 + i;
        int r = seg * 8 + lr8;
        gload_lds16(Kp + (size_t)(t * 128 + r) * 64 + ((lc8 ^ (r & 7)) * 8), Ks + seg * 512);
      }
#pragma unroll
      for (int i = 0; i < 4; ++i) {  // V^T tile [64][128]
        int seg = wid * 4 + i;
        int r = seg * 4 + lr16;
        gload_lds16(Vp + (size_t)r * 2048 + t * 128 + ((lc16 ^ (r & 15)) * 8), Vs + seg * 512);
      }
      __syncthreads();  // staging visible (vmcnt drained by barrier semantics)

      // padding-mask additive bias (kv = rt*16 + quad*4 + i), L1-resident
      floatx4 mbias[8];
#pragma unroll
      for (int rt = 0; rt < 8; ++rt) {
        floatx4 mm = *(const floatx4*)&mp[t * 128 + rt * 16 + quad * 4];
        mbias[rt] = (fone - mm) * -1.0e9f;
      }

      // S^T: [kv=128][q=16 per wave]
      floatx4 sc[8];
#pragma unroll
      for (int rt = 0; rt < 8; ++rt) {
        int kr = rt * 16 + col;
        short8 kf0 = *(const short8*)&Ks[kr * 64 + ((quad ^ (col & 7)) * 8)];
        short8 kf1 = *(const short8*)&Ks[kr * 64 + (((4 + quad) ^ (col & 7)) * 8)];
        floatx4 s0 = MFMA16(kf0, qf[0], fzero);
        s0 = MFMA16(kf1, qf[1], s0);
        sc[rt] = s0 + mbias[rt];
      }
      if (t == tdiag) {  // diagonal tile: causal mask, exactly -1e9 like the reference
        int qg = q0 + wid * 16 + col;
#pragma unroll
        for (int rt = 0; rt < 8; ++rt)
#pragma unroll
          for (int i = 0; i < 4; ++i)
            if (t * 128 + rt * 16 + quad * 4 + i > qg) sc[rt][i] = -1.0e9f;
      }

      // online softmax (per-lane q row stats; reduce over quad via 2 shuffles)
      float mt = -1e30f;
#pragma unroll
      for (int rt = 0; rt < 8; ++rt)
        mt = fmaxf(mt, fmaxf(fmaxf(sc[rt][0], sc[rt][1]), fmaxf(sc[rt][2], sc[rt][3])));
      mt = fmaxf(mt, __shfl_xor(mt, 16));
      mt = fmaxf(mt, __shfl_xor(mt, 32));
      float mn = fmaxf(mrow, mt);
      float alpha = __expf(mrow - mn);
      mrow = mn;
      float sum = 0.f;
#pragma unroll
      for (int rt = 0; rt < 8; ++rt)
#pragma unroll
        for (int i = 0; i < 4; ++i) {
          float p = __expf(sc[rt][i] - mn);
          sc[rt][i] = p;
          sum += p;
        }
      sum += __shfl_xor(sum, 16);
      sum += __shfl_xor(sum, 32);
      lrow = lrow * alpha + sum;
#pragma unroll
      for (int dt = 0; dt < 4; ++dt) o[dt] *= alpha;
      // write P rows (own wave) swizzled: 8B at chunk (rt*2 + quad>>1) ^ col, half quad&1
      {
        int qloc = wid * 16 + col;
#pragma unroll
        for (int rt = 0; rt < 8; ++rt) {
          ushortx4 pk;
#pragma unroll
          for (int i = 0; i < 4; ++i) pk[i] = f2bf(sc[rt][i]);
          int chunk = (rt * 2 + (quad >> 1)) ^ col;
          *(ushortx4*)&Ps[qloc * 128 + chunk * 8 + (quad & 1) * 4] = pk;
        }
      }
      // PV: O^T[d][q] += V^T * P^T (own-wave P rows; DS in-order per wave, no barrier)
#pragma unroll
      for (int ks = 0; ks < 4; ++ks) {
        int ch = ks * 4 + quad;
        short8 pf = *(const short8*)&Ps[(wid * 16 + col) * 128 + ((ch ^ col) * 8)];
#pragma unroll
        for (int dt = 0; dt < 4; ++dt) {
          short8 vf = *(const short8*)&Vs[(dt * 16 + col) * 128 + ((ch ^ col) * 8)];
          o[dt] = MFMA16(vf, pf, o[dt]);
        }
      }
    }

    // epilogue: O^T regs: d = dt*16 + quad*4 + i, q = wid*16 + col
    {
      float inv = 1.0f / lrow;
      int qg = q0 + wid * 16 + col;
      unsigned short* dst = O + ((size_t)(b * 2048 + qg)) * 1024 + h * 64;
#pragma unroll
      for (int dt = 0; dt < 4; ++dt) {
        ushortx4 pk;
#pragma unroll
        for (int i = 0; i < 4; ++i) pk[i] = f2bf(o[dt][i] * inv);
        *(ushortx4*)&dst[dt * 16 + quad * 4] = pk;
      }
    }
  }
}

// ---------------- launch ----------------
extern "C" void kernel_launch(void* const* d_in, const int* in_sizes, int n_in,
                              void* d_out, int out_size, void* d_ws, size_t ws_size,
                              hipStream_t stream) {
  (void)in_sizes; (void)n_in; (void)out_size; (void)ws_size;
  const float* x  = (const float*)d_in[0];
  const float* mask = (const float*)d_in[1];
  const float* Wq = (const float*)d_in[2];
  const float* bq = (const float*)d_in[3];
  const float* Wk = (const float*)d_in[4];
  const float* bk = (const float*)d_in[5];
  const float* Wv = (const float*)d_in[6];
  const float* bv = (const float*)d_in[7];
  const float* Wo = (const float*)d_in[8];
  const float* bo = (const float*)d_in[9];
  float* out = (float*)d_out;

  char* ws = (char*)d_ws;
  unsigned short* xb    = (unsigned short*)(ws);                    // 8 MB
  unsigned short* Wqkvt = (unsigned short*)(ws + (8u << 20));       // 6 MB
  unsigned short* Wot   = (unsigned short*)(ws + (14u << 20));      // 2 MB
  unsigned short* Qb    = (unsigned short*)(ws + (16u << 20));      // 8 MB
  unsigned short* Kb    = (unsigned short*)(ws + (24u << 20));      // 8 MB
  unsigned short* Vtb   = (unsigned short*)(ws + (32u << 20));      // 8 MB
  unsigned short* Ao    = (unsigned short*)(ws + (40u << 20));      // 8 MB (48 MB total)

  convert_x<<<4096, 256, 0, stream>>>(x, xb);
  transpose_w<<<dim3(32, 32, 4), dim3(32, 8), 0, stream>>>(Wq, Wk, Wv, Wo, Wqkvt, Wot);
  gemm_qkv<<<dim3(32, 24), 256, 0, stream>>>(xb, Wqkvt, bq, bk, bv, Qb, Kb, Vtb);
  flash_attn<<<dim3(16, 32), 256, 0, stream>>>(Qb, Kb, Vtb, mask, Ao);
  gemm_out<<<dim3(32, 8), 256, 0, stream>>>(Ao, Wot, bo, out);
}